// Round 1
// baseline (583.571 us; speedup 1.0000x reference)
//
#include <hip/hip_runtime.h>
#include <cstdint>

#define NROWS 8192
#define FDIM  512

typedef __attribute__((ext_vector_type(8))) unsigned short u16x8;
typedef __attribute__((ext_vector_type(8))) __bf16 bf16x8;
typedef __attribute__((ext_vector_type(4))) float f32x4;

__device__ __forceinline__ unsigned short f2bf(float f) {
    unsigned u = __float_as_uint(f);
    u += 0x7fffu + ((u >> 16) & 1u);   // RNE; inputs are finite/normal
    return (unsigned short)(u >> 16);
}

__device__ __forceinline__ void gload16(const void* g, void* l) {
    __builtin_amdgcn_global_load_lds(
        (__attribute__((address_space(1))) unsigned int*)g,
        (__attribute__((address_space(3))) unsigned int*)l,
        16, 0, 0);
}

// Pass 1: column sums of graph (deg) + bf16 transposed rewrite gT[i,j] = graph[j,i]
__global__ __launch_bounds__(256) void deg_transpose_kernel(
    const float* __restrict__ graph, unsigned short* __restrict__ gT,
    float* __restrict__ deg) {
    __shared__ float tile[64][65];
    __shared__ float colsum[64];
    const int t  = threadIdx.x;
    const int i0 = blockIdx.x * 64;   // column block of graph
    const int j0 = blockIdx.y * 64;   // row block of graph
    if (t < 64) colsum[t] = 0.f;
    __syncthreads();
    {   // coalesced float4 load of 64x64 tile
        const int c4 = (t & 15) * 4;
        const int r  = t >> 4;
        #pragma unroll
        for (int p = 0; p < 4; ++p) {
            const int rr = r + p * 16;
            const float4 v = *(const float4*)&graph[(size_t)(j0 + rr) * NROWS + i0 + c4];
            tile[rr][c4 + 0] = v.x; tile[rr][c4 + 1] = v.y;
            tile[rr][c4 + 2] = v.z; tile[rr][c4 + 3] = v.w;
        }
    }
    __syncthreads();
    {   // per-column partial sums (4 threads per column)
        const int c = t & 63, q = t >> 6;
        float s = 0.f;
        #pragma unroll
        for (int r2 = 0; r2 < 16; ++r2) s += tile[q * 16 + r2][c];
        atomicAdd(&colsum[c], s);
    }
    {   // transposed bf16 write, 8B per thread, coalesced
        const int jj  = (t & 15) * 4;
        const int c2b = t >> 4;
        #pragma unroll
        for (int p = 0; p < 4; ++p) {
            const int c2 = c2b + p * 16;
            ushort4 o;
            o.x = f2bf(tile[jj + 0][c2]);
            o.y = f2bf(tile[jj + 1][c2]);
            o.z = f2bf(tile[jj + 2][c2]);
            o.w = f2bf(tile[jj + 3][c2]);
            *(ushort4*)&gT[(size_t)(i0 + c2) * NROWS + j0 + jj] = o;
        }
    }
    __syncthreads();
    if (t < 64) atomicAdd(&deg[i0 + t], colsum[t]);
}

// Generic transpose (+ optional row scale by rsqrt(deg)) fp32 -> bf16
__global__ __launch_bounds__(256) void transpose_scale_kernel(
    const float* __restrict__ src, unsigned short* __restrict__ dst,
    int rows, int cols, const float* __restrict__ degv) {
    __shared__ float tile[64][65];
    __shared__ float drow[64];
    const int t  = threadIdx.x;
    const int c0 = blockIdx.x * 64;
    const int r0 = blockIdx.y * 64;
    if (t < 64) drow[t] = degv ? rsqrtf(degv[r0 + t]) : 1.0f;
    __syncthreads();
    {
        const int c4 = (t & 15) * 4;
        const int r  = t >> 4;
        #pragma unroll
        for (int p = 0; p < 4; ++p) {
            const int rr = r + p * 16;
            const float4 v = *(const float4*)&src[(size_t)(r0 + rr) * cols + c0 + c4];
            const float s = drow[rr];
            tile[rr][c4 + 0] = v.x * s; tile[rr][c4 + 1] = v.y * s;
            tile[rr][c4 + 2] = v.z * s; tile[rr][c4 + 3] = v.w * s;
        }
    }
    __syncthreads();
    {
        const int jj  = (t & 15) * 4;
        const int c2b = t >> 4;
        #pragma unroll
        for (int p = 0; p < 4; ++p) {
            const int c2 = c2b + p * 16;
            ushort4 o;
            o.x = f2bf(tile[jj + 0][c2]);
            o.y = f2bf(tile[jj + 1][c2]);
            o.z = f2bf(tile[jj + 2][c2]);
            o.w = f2bf(tile[jj + 3][c2]);
            *(ushort4*)&dst[(size_t)(c0 + c2) * rows + r0 + jj] = o;
        }
    }
}

// NT GEMM: C[m][n] = sum_k A[m*lda+k]*B[n*ldb+k]; bf16 inputs (k-contiguous).
// 128x128 block tile, BK=64, 256 threads (2x2 waves of 64x64), 16x16x32 MFMA.
// FINAL=false: write bf16 C. FINAL=true: write fp32 rsqrt(deg[row])*acc + bias[col].
template <bool FINAL>
__global__ __launch_bounds__(256) void gemm_nt_kernel(
    const unsigned short* __restrict__ A, const unsigned short* __restrict__ B,
    int K, int lda, int ldb,
    unsigned short* __restrict__ Cb, float* __restrict__ Cf,
    const float* __restrict__ degv, const float* __restrict__ bias, int ldc) {
    __shared__ unsigned short As[2 * 128 * 32];   // [ks][m][32]
    __shared__ unsigned short Bs[2 * 128 * 32];   // [ks][n][32]
    const int t    = threadIdx.x;
    const int w    = t >> 6, lane = t & 63;
    const int wr   = w >> 1, wc = w & 1;
    const int lrow = lane & 15, quad = lane >> 4;
    const int i0   = blockIdx.x * 128, f0 = blockIdx.y * 128;
    f32x4 acc[4][4] = {};

    for (int k0 = 0; k0 < K; k0 += 64) {
        // stage 16KB A + 16KB B via global_load_lds (16B/lane, lane-contiguous LDS)
        #pragma unroll
        for (int i = 0; i < 4; ++i) {
            const int q  = t + i * 256;           // chunk id == LDS chunk position
            const int ks = q >> 9, rem = q & 511;
            const int m  = rem >> 2, kq = rem & 3;
            const int gofs = k0 + ks * 32 + kq * 8;
            gload16(&A[(size_t)(i0 + m) * lda + gofs], &As[(size_t)(w * 64 + i * 256) * 8]);
            gload16(&B[(size_t)(f0 + m) * ldb + gofs], &Bs[(size_t)(w * 64 + i * 256) * 8]);
        }
        __syncthreads();
        #pragma unroll
        for (int ks = 0; ks < 2; ++ks) {
            bf16x8 af[4], bfr[4];
            #pragma unroll
            for (int mt = 0; mt < 4; ++mt)
                af[mt] = __builtin_bit_cast(bf16x8,
                    *(const u16x8*)&As[ks * 4096 + (wr * 64 + mt * 16 + lrow) * 32 + quad * 8]);
            #pragma unroll
            for (int nt = 0; nt < 4; ++nt)
                bfr[nt] = __builtin_bit_cast(bf16x8,
                    *(const u16x8*)&Bs[ks * 4096 + (wc * 64 + nt * 16 + lrow) * 32 + quad * 8]);
            #pragma unroll
            for (int mt = 0; mt < 4; ++mt)
                #pragma unroll
                for (int nt = 0; nt < 4; ++nt)
                    acc[mt][nt] = __builtin_amdgcn_mfma_f32_16x16x32_bf16(
                        af[mt], bfr[nt], acc[mt][nt], 0, 0, 0);
        }
        __syncthreads();
    }
    // epilogue: C/D layout col=lane&15, row=quad*4+reg (m89-verified)
    #pragma unroll
    for (int mt = 0; mt < 4; ++mt) {
        #pragma unroll
        for (int nt = 0; nt < 4; ++nt) {
            const int col = f0 + wc * 64 + nt * 16 + lrow;
            #pragma unroll
            for (int r = 0; r < 4; ++r) {
                const int row = i0 + wr * 64 + mt * 16 + quad * 4 + r;
                if (FINAL) {
                    const float dsc = rsqrtf(degv[row]);
                    Cf[(size_t)row * ldc + col] = dsc * acc[mt][nt][r] + bias[col];
                } else {
                    Cb[(size_t)row * ldc + col] = f2bf(acc[mt][nt][r]);
                }
            }
        }
    }
}

extern "C" void kernel_launch(void* const* d_in, const int* in_sizes, int n_in,
                              void* d_out, int out_size, void* d_ws, size_t ws_size,
                              hipStream_t stream) {
    const float* x      = (const float*)d_in[0];
    const float* graph  = (const float*)d_in[1];
    const float* weight = (const float*)d_in[2];
    const float* bias   = (const float*)d_in[3];
    float* out = (float*)d_out;

    char* ws = (char*)d_ws;
    const size_t GT_B  = (size_t)NROWS * NROWS * 2;   // 134.2 MB: gT bf16
    const size_t XST_B = (size_t)FDIM * NROWS * 2;    // 8.4 MB: xsT bf16
    const size_t WT_B  = (size_t)FDIM * FDIM * 2;     // 0.5 MB: wT bf16
    const size_t TB_B  = (size_t)NROWS * FDIM * 2;    // 8.4 MB: T bf16
    unsigned short* gT  = (unsigned short*)(ws);
    unsigned short* xsT = (unsigned short*)(ws + GT_B);
    unsigned short* wT  = (unsigned short*)(ws + GT_B + XST_B);
    unsigned short* Tb  = (unsigned short*)(ws + GT_B + XST_B + WT_B);
    float* deg          = (float*)(ws + GT_B + XST_B + WT_B + TB_B);

    hipMemsetAsync(deg, 0, NROWS * sizeof(float), stream);
    hipLaunchKernelGGL(deg_transpose_kernel, dim3(NROWS / 64, NROWS / 64), dim3(256), 0, stream,
                       graph, gT, deg);
    hipLaunchKernelGGL(transpose_scale_kernel, dim3(FDIM / 64, NROWS / 64), dim3(256), 0, stream,
                       x, xsT, NROWS, FDIM, deg);
    hipLaunchKernelGGL(transpose_scale_kernel, dim3(FDIM / 64, FDIM / 64), dim3(256), 0, stream,
                       weight, wT, FDIM, FDIM, (const float*)nullptr);
    // T = G^T @ (d*x):  M=8192, N=512, K=8192
    hipLaunchKernelGGL(gemm_nt_kernel<false>, dim3(NROWS / 128, FDIM / 128), dim3(256), 0, stream,
                       gT, xsT, NROWS, NROWS, NROWS, Tb, (float*)nullptr,
                       (const float*)nullptr, (const float*)nullptr, FDIM);
    // y = diag(d) * (T @ W) + bias:  M=8192, N=512, K=512
    hipLaunchKernelGGL(gemm_nt_kernel<true>, dim3(NROWS / 128, FDIM / 128), dim3(256), 0, stream,
                       Tb, wT, FDIM, FDIM, FDIM, (unsigned short*)nullptr, out,
                       deg, bias, FDIM);
}

// Round 2
// 544.327 us; speedup vs baseline: 1.0721x; 1.0721x over previous
//
#include <hip/hip_runtime.h>
#include <cstdint>

#define NROWS 8192
#define FDIM  512

typedef __attribute__((ext_vector_type(8))) unsigned short u16x8;
typedef __attribute__((ext_vector_type(8))) __bf16 bf16x8;
typedef __attribute__((ext_vector_type(4))) float f32x4;

__device__ __forceinline__ unsigned short f2bf(float f) {
    unsigned u = __float_as_uint(f);
    u += 0x7fffu + ((u >> 16) & 1u);   // RNE; inputs are finite/normal
    return (unsigned short)(u >> 16);
}

__device__ __forceinline__ float bf2f(unsigned short h) {
    return __uint_as_float((unsigned)h << 16);
}

__device__ __forceinline__ void gload16(const void* g, void* l) {
    __builtin_amdgcn_global_load_lds(
        (__attribute__((address_space(1))) unsigned int*)g,
        (__attribute__((address_space(3))) unsigned int*)l,
        16, 0, 0);
}

// Pure tiled transpose fp32 -> bf16: gT[i][j] = bf16(graph[j][i]). No deg, no atomics.
__global__ __launch_bounds__(256) void transpose_bf16_kernel(
    const float* __restrict__ graph, unsigned short* __restrict__ gT) {
    __shared__ float tile[64][65];
    const int t  = threadIdx.x;
    const int i0 = blockIdx.x * 64;   // column block of graph = row block of gT
    const int j0 = blockIdx.y * 64;   // row block of graph
    {
        const int c4 = (t & 15) * 4;
        const int r  = t >> 4;
        #pragma unroll
        for (int p = 0; p < 4; ++p) {
            const int rr = r + p * 16;
            const float4 v = *(const float4*)&graph[(size_t)(j0 + rr) * NROWS + i0 + c4];
            tile[rr][c4 + 0] = v.x; tile[rr][c4 + 1] = v.y;
            tile[rr][c4 + 2] = v.z; tile[rr][c4 + 3] = v.w;
        }
    }
    __syncthreads();
    {
        const int jj  = (t & 15) * 4;
        const int c2b = t >> 4;
        #pragma unroll
        for (int p = 0; p < 4; ++p) {
            const int c2 = c2b + p * 16;
            ushort4 o;
            o.x = f2bf(tile[jj + 0][c2]);
            o.y = f2bf(tile[jj + 1][c2]);
            o.z = f2bf(tile[jj + 2][c2]);
            o.w = f2bf(tile[jj + 3][c2]);
            *(ushort4*)&gT[(size_t)(i0 + c2) * NROWS + j0 + jj] = o;
        }
    }
}

// deg[i] = sum_j gT[i][j] (bf16 row sums, fp32 accumulate). One wave per row.
__global__ __launch_bounds__(256) void rowsum_kernel(
    const unsigned short* __restrict__ gT, float* __restrict__ deg) {
    const int w = threadIdx.x >> 6, lane = threadIdx.x & 63;
    const int row = blockIdx.x * 4 + w;
    const unsigned short* p = &gT[(size_t)row * NROWS];
    float s = 0.f;
    #pragma unroll 4
    for (int it = 0; it < 16; ++it) {
        const u16x8 v = *(const u16x8*)&p[(it * 64 + lane) * 8];
        #pragma unroll
        for (int j = 0; j < 8; ++j) s += bf2f(v[j]);
    }
    #pragma unroll
    for (int off = 32; off; off >>= 1) s += __shfl_down(s, off);
    if (lane == 0) deg[row] = s;
}

// Generic transpose (+ optional row scale by rsqrt(deg)) fp32 -> bf16
__global__ __launch_bounds__(256) void transpose_scale_kernel(
    const float* __restrict__ src, unsigned short* __restrict__ dst,
    int rows, int cols, const float* __restrict__ degv) {
    __shared__ float tile[64][65];
    __shared__ float drow[64];
    const int t  = threadIdx.x;
    const int c0 = blockIdx.x * 64;
    const int r0 = blockIdx.y * 64;
    if (t < 64) drow[t] = degv ? rsqrtf(degv[r0 + t]) : 1.0f;
    __syncthreads();
    {
        const int c4 = (t & 15) * 4;
        const int r  = t >> 4;
        #pragma unroll
        for (int p = 0; p < 4; ++p) {
            const int rr = r + p * 16;
            const float4 v = *(const float4*)&src[(size_t)(r0 + rr) * cols + c0 + c4];
            const float s = drow[rr];
            tile[rr][c4 + 0] = v.x * s; tile[rr][c4 + 1] = v.y * s;
            tile[rr][c4 + 2] = v.z * s; tile[rr][c4 + 3] = v.w * s;
        }
    }
    __syncthreads();
    {
        const int jj  = (t & 15) * 4;
        const int c2b = t >> 4;
        #pragma unroll
        for (int p = 0; p < 4; ++p) {
            const int c2 = c2b + p * 16;
            ushort4 o;
            o.x = f2bf(tile[jj + 0][c2]);
            o.y = f2bf(tile[jj + 1][c2]);
            o.z = f2bf(tile[jj + 2][c2]);
            o.w = f2bf(tile[jj + 3][c2]);
            *(ushort4*)&dst[(size_t)(c0 + c2) * rows + r0 + jj] = o;
        }
    }
}

// NT GEMM: C[m][n] = sum_k A[m*lda+k]*B[n*ldb+k]; bf16 inputs (k-contiguous).
// 128x64 block tile (BM=128, BN=64), BK=64, 256 threads = 2x2 waves, each wave 64x32.
// Grid (M/128, N/64) = 512 blocks -> 2 blocks/CU, 2 waves/SIMD.
// FINAL=false: write bf16 C. FINAL=true: write fp32 rsqrt(deg[row])*acc + bias[col].
template <bool FINAL>
__global__ __launch_bounds__(256) void gemm_nt_kernel(
    const unsigned short* __restrict__ A, const unsigned short* __restrict__ B,
    int K, int lda, int ldb,
    unsigned short* __restrict__ Cb, float* __restrict__ Cf,
    const float* __restrict__ degv, const float* __restrict__ bias, int ldc) {
    __shared__ unsigned short As[2 * 128 * 32];   // [ks][m][32] : 16 KB
    __shared__ unsigned short Bs[2 * 64 * 32];    // [ks][n][32] :  8 KB
    const int t    = threadIdx.x;
    const int w    = t >> 6, lane = t & 63;
    const int wr   = w >> 1, wc = w & 1;
    const int lrow = lane & 15, quad = lane >> 4;
    const int i0   = blockIdx.x * 128, f0 = blockIdx.y * 64;
    f32x4 acc[4][2] = {};

    for (int k0 = 0; k0 < K; k0 += 64) {
        // A-tile: 128x64 bf16 = 1024 x 16B chunks; chunk q lands at As + q*16B
        #pragma unroll
        for (int i = 0; i < 4; ++i) {
            const int q  = t + i * 256;
            const int ks = q >> 9, rem = q & 511;
            const int m  = rem >> 2, kq = rem & 3;
            gload16(&A[(size_t)(i0 + m) * lda + k0 + ks * 32 + kq * 8],
                    &As[(size_t)(w * 64 + i * 256) * 8]);
        }
        // B-tile: 64x64 bf16 = 512 x 16B chunks
        #pragma unroll
        for (int i = 0; i < 2; ++i) {
            const int q  = t + i * 256;
            const int ks = q >> 8, rem = q & 255;
            const int n  = rem >> 2, kq = rem & 3;
            gload16(&B[(size_t)(f0 + n) * ldb + k0 + ks * 32 + kq * 8],
                    &Bs[(size_t)(w * 64 + i * 256) * 8]);
        }
        __syncthreads();
        #pragma unroll
        for (int ks = 0; ks < 2; ++ks) {
            bf16x8 af[4], bfr[2];
            #pragma unroll
            for (int mt = 0; mt < 4; ++mt)
                af[mt] = __builtin_bit_cast(bf16x8,
                    *(const u16x8*)&As[ks * 4096 + (wr * 64 + mt * 16 + lrow) * 32 + quad * 8]);
            #pragma unroll
            for (int nt = 0; nt < 2; ++nt)
                bfr[nt] = __builtin_bit_cast(bf16x8,
                    *(const u16x8*)&Bs[ks * 2048 + (wc * 32 + nt * 16 + lrow) * 32 + quad * 8]);
            #pragma unroll
            for (int mt = 0; mt < 4; ++mt)
                #pragma unroll
                for (int nt = 0; nt < 2; ++nt)
                    acc[mt][nt] = __builtin_amdgcn_mfma_f32_16x16x32_bf16(
                        af[mt], bfr[nt], acc[mt][nt], 0, 0, 0);
        }
        __syncthreads();
    }
    // epilogue: C/D layout col=lane&15, row=quad*4+reg (m89-verified)
    #pragma unroll
    for (int mt = 0; mt < 4; ++mt) {
        #pragma unroll
        for (int nt = 0; nt < 2; ++nt) {
            const int col = f0 + wc * 32 + nt * 16 + lrow;
            #pragma unroll
            for (int r = 0; r < 4; ++r) {
                const int row = i0 + wr * 64 + mt * 16 + quad * 4 + r;
                if (FINAL) {
                    const float dsc = rsqrtf(degv[row]);
                    Cf[(size_t)row * ldc + col] = dsc * acc[mt][nt][r] + bias[col];
                } else {
                    Cb[(size_t)row * ldc + col] = f2bf(acc[mt][nt][r]);
                }
            }
        }
    }
}

extern "C" void kernel_launch(void* const* d_in, const int* in_sizes, int n_in,
                              void* d_out, int out_size, void* d_ws, size_t ws_size,
                              hipStream_t stream) {
    const float* x      = (const float*)d_in[0];
    const float* graph  = (const float*)d_in[1];
    const float* weight = (const float*)d_in[2];
    const float* bias   = (const float*)d_in[3];
    float* out = (float*)d_out;

    char* ws = (char*)d_ws;
    const size_t GT_B  = (size_t)NROWS * NROWS * 2;   // 134.2 MB: gT bf16
    const size_t XST_B = (size_t)FDIM * NROWS * 2;    // 8.4 MB: xsT bf16
    const size_t WT_B  = (size_t)FDIM * FDIM * 2;     // 0.5 MB: wT bf16
    const size_t TB_B  = (size_t)NROWS * FDIM * 2;    // 8.4 MB: T bf16
    unsigned short* gT  = (unsigned short*)(ws);
    unsigned short* xsT = (unsigned short*)(ws + GT_B);
    unsigned short* wT  = (unsigned short*)(ws + GT_B + XST_B);
    unsigned short* Tb  = (unsigned short*)(ws + GT_B + XST_B + WT_B);
    float* deg          = (float*)(ws + GT_B + XST_B + WT_B + TB_B);

    hipLaunchKernelGGL(transpose_bf16_kernel, dim3(NROWS / 64, NROWS / 64), dim3(256), 0, stream,
                       graph, gT);
    hipLaunchKernelGGL(rowsum_kernel, dim3(NROWS / 4), dim3(256), 0, stream, gT, deg);
    hipLaunchKernelGGL(transpose_scale_kernel, dim3(FDIM / 64, NROWS / 64), dim3(256), 0, stream,
                       x, xsT, NROWS, FDIM, deg);
    hipLaunchKernelGGL(transpose_scale_kernel, dim3(FDIM / 64, FDIM / 64), dim3(256), 0, stream,
                       weight, wT, FDIM, FDIM, (const float*)nullptr);
    // T = G^T @ (d*x):  M=8192, N=512, K=8192
    hipLaunchKernelGGL(gemm_nt_kernel<false>, dim3(NROWS / 128, FDIM / 64), dim3(256), 0, stream,
                       gT, xsT, NROWS, NROWS, NROWS, Tb, (float*)nullptr,
                       (const float*)nullptr, (const float*)nullptr, FDIM);
    // y = diag(d) * (T @ W) + bias:  M=8192, N=512, K=512
    hipLaunchKernelGGL(gemm_nt_kernel<true>, dim3(NROWS / 128, FDIM / 64), dim3(256), 0, stream,
                       Tb, wT, FDIM, FDIM, FDIM, (unsigned short*)nullptr, out,
                       deg, bias, FDIM);
}

// Round 3
// 528.120 us; speedup vs baseline: 1.1050x; 1.0307x over previous
//
#include <hip/hip_runtime.h>
#include <cstdint>

#define NROWS 8192
#define FDIM  512

typedef __attribute__((ext_vector_type(8))) unsigned short u16x8;
typedef __attribute__((ext_vector_type(8))) __bf16 bf16x8;
typedef __attribute__((ext_vector_type(4))) float f32x4;

__device__ __forceinline__ unsigned short f2bf(float f) {
    unsigned u = __float_as_uint(f);
    u += 0x7fffu + ((u >> 16) & 1u);   // RNE; inputs are finite/normal
    return (unsigned short)(u >> 16);
}

__device__ __forceinline__ float bf2f(unsigned short h) {
    return __uint_as_float((unsigned)h << 16);
}

__device__ __forceinline__ void gload16(const void* g, void* l) {
    __builtin_amdgcn_global_load_lds(
        (__attribute__((address_space(1))) unsigned int*)g,
        (__attribute__((address_space(3))) unsigned int*)l,
        16, 0, 0);
}

// Transpose fp32 -> bf16: gT[i][j] = bf16(graph[j][i]).
// Tile = 128 j-rows x 64 i-cols. Writes 256B contiguous segments (ushort8/lane).
__global__ __launch_bounds__(256) void transpose_bf16_kernel(
    const float* __restrict__ graph, unsigned short* __restrict__ gT) {
    __shared__ float tile[128][65];   // [j][i], odd pad: b32 LDS ops, <=4-way banks
    const int t  = threadIdx.x;
    const int i0 = blockIdx.x * 64;
    const int j0 = blockIdx.y * 128;
    {   // phase 1: coalesced float4 reads, 256B/row segments
        const int c4 = (t & 15) * 4;
        const int r  = t >> 4;
        #pragma unroll
        for (int p = 0; p < 8; ++p) {
            const int rr = r + p * 16;   // 0..127
            const float4 v = *(const float4*)&graph[(size_t)(j0 + rr) * NROWS + i0 + c4];
            tile[rr][c4 + 0] = v.x; tile[rr][c4 + 1] = v.y;
            tile[rr][c4 + 2] = v.z; tile[rr][c4 + 3] = v.w;
        }
    }
    __syncthreads();
    {   // phase 2: ushort8 stores, 256B/row segments (16 lanes x 16B)
        const int ci = t & 15;           // j-chunk: j = ci*8 .. ci*8+7
        const int ir = t >> 4;           // 0..15
        #pragma unroll
        for (int p = 0; p < 4; ++p) {
            const int i = ir + p * 16;   // 0..63
            u16x8 o;
            #pragma unroll
            for (int q = 0; q < 8; ++q) o[q] = f2bf(tile[ci * 8 + q][i]);
            *(u16x8*)&gT[(size_t)(i0 + i) * NROWS + j0 + ci * 8] = o;
        }
    }
}

// deg[i] = sum_j gT[i][j] (bf16 row sums, fp32 accumulate). One wave per row.
__global__ __launch_bounds__(256) void rowsum_kernel(
    const unsigned short* __restrict__ gT, float* __restrict__ deg) {
    const int w = threadIdx.x >> 6, lane = threadIdx.x & 63;
    const int row = blockIdx.x * 4 + w;
    const unsigned short* p = &gT[(size_t)row * NROWS];
    float s = 0.f;
    #pragma unroll 4
    for (int it = 0; it < 16; ++it) {
        const u16x8 v = *(const u16x8*)&p[(it * 64 + lane) * 8];
        #pragma unroll
        for (int j = 0; j < 8; ++j) s += bf2f(v[j]);
    }
    #pragma unroll
    for (int off = 32; off; off >>= 1) s += __shfl_down(s, off);
    if (lane == 0) deg[row] = s;
}

// Generic transpose (+ optional row scale by rsqrt(deg)) fp32 -> bf16
__global__ __launch_bounds__(256) void transpose_scale_kernel(
    const float* __restrict__ src, unsigned short* __restrict__ dst,
    int rows, int cols, const float* __restrict__ degv) {
    __shared__ float tile[64][65];
    __shared__ float drow[64];
    const int t  = threadIdx.x;
    const int c0 = blockIdx.x * 64;
    const int r0 = blockIdx.y * 64;
    if (t < 64) drow[t] = degv ? rsqrtf(degv[r0 + t]) : 1.0f;
    __syncthreads();
    {
        const int c4 = (t & 15) * 4;
        const int r  = t >> 4;
        #pragma unroll
        for (int p = 0; p < 4; ++p) {
            const int rr = r + p * 16;
            const float4 v = *(const float4*)&src[(size_t)(r0 + rr) * cols + c0 + c4];
            const float s = drow[rr];
            tile[rr][c4 + 0] = v.x * s; tile[rr][c4 + 1] = v.y * s;
            tile[rr][c4 + 2] = v.z * s; tile[rr][c4 + 3] = v.w * s;
        }
    }
    __syncthreads();
    {
        const int jj  = (t & 15) * 4;
        const int c2b = t >> 4;
        #pragma unroll
        for (int p = 0; p < 4; ++p) {
            const int c2 = c2b + p * 16;
            ushort4 o;
            o.x = f2bf(tile[jj + 0][c2]);
            o.y = f2bf(tile[jj + 1][c2]);
            o.z = f2bf(tile[jj + 2][c2]);
            o.w = f2bf(tile[jj + 3][c2]);
            *(ushort4*)&dst[(size_t)(c0 + c2) * rows + r0 + jj] = o;
        }
    }
}

// NT GEMM: C[m][n] = sum_k A[m*lda+k]*B[n*ldb+k]; bf16 inputs (k-contiguous).
// BM=128, BN template (64 or 128), BK=64, 256 threads = 2x2 waves.
// kbeg = blockIdx.z * klen (split-K); z-th fp32 partial at Cf + z*zstride.
// MODE 1: fp32 final = rsqrt(deg[row])*acc + bias[col]. MODE 2: fp32 raw partial.
template <int BN, int MODE>
__global__ __launch_bounds__(256) void gemm_nt_kernel(
    const unsigned short* __restrict__ A, const unsigned short* __restrict__ B,
    int klen, int lda, int ldb, float* __restrict__ Cf, size_t zstride,
    const float* __restrict__ degv, const float* __restrict__ bias, int ldc) {
    __shared__ unsigned short As[2 * 128 * 32];    // [ks][m][32]
    __shared__ unsigned short Bs[2 * BN * 32];     // [ks][n][32]
    constexpr int NF = BN / 32;                    // n-fragments per wave
    const int t    = threadIdx.x;
    const int w    = t >> 6, lane = t & 63;
    const int wr   = w >> 1, wc = w & 1;
    const int lrow = lane & 15, quad = lane >> 4;
    const int i0   = blockIdx.x * 128, f0 = blockIdx.y * BN;
    const int kbeg = blockIdx.z * klen;
    f32x4 acc[4][NF] = {};

    for (int k0 = kbeg; k0 < kbeg + klen; k0 += 64) {
        #pragma unroll
        for (int i = 0; i < 4; ++i) {              // A: 1024 x 16B chunks
            const int q  = t + i * 256;
            const int ks = q >> 9, rem = q & 511;
            const int m  = rem >> 2, kq = rem & 3;
            gload16(&A[(size_t)(i0 + m) * lda + k0 + ks * 32 + kq * 8],
                    &As[(size_t)(w * 64 + i * 256) * 8]);
        }
        #pragma unroll
        for (int i = 0; i < BN / 32; ++i) {        // B: BN*8 x 16B chunks
            const int q  = t + i * 256;
            const int ks = q / (BN * 4), rem = q % (BN * 4);
            const int n  = rem >> 2, kq = rem & 3;
            gload16(&B[(size_t)(f0 + n) * ldb + k0 + ks * 32 + kq * 8],
                    &Bs[(size_t)(w * 64 + i * 256) * 8]);
        }
        __syncthreads();
        #pragma unroll
        for (int ks = 0; ks < 2; ++ks) {
            bf16x8 af[4], bfr[NF];
            #pragma unroll
            for (int mt = 0; mt < 4; ++mt)
                af[mt] = __builtin_bit_cast(bf16x8,
                    *(const u16x8*)&As[ks * 4096 + (wr * 64 + mt * 16 + lrow) * 32 + quad * 8]);
            #pragma unroll
            for (int nt = 0; nt < NF; ++nt)
                bfr[nt] = __builtin_bit_cast(bf16x8,
                    *(const u16x8*)&Bs[ks * (BN * 32) + (wc * (BN / 2) + nt * 16 + lrow) * 32 + quad * 8]);
            #pragma unroll
            for (int mt = 0; mt < 4; ++mt)
                #pragma unroll
                for (int nt = 0; nt < NF; ++nt)
                    acc[mt][nt] = __builtin_amdgcn_mfma_f32_16x16x32_bf16(
                        af[mt], bfr[nt], acc[mt][nt], 0, 0, 0);
        }
        __syncthreads();
    }
    float* __restrict__ Co = Cf + (size_t)blockIdx.z * zstride;
    // epilogue: C/D layout col=lane&15, row=quad*4+reg (m89-verified)
    #pragma unroll
    for (int mt = 0; mt < 4; ++mt) {
        #pragma unroll
        for (int nt = 0; nt < NF; ++nt) {
            const int col = f0 + wc * (BN / 2) + nt * 16 + lrow;
            #pragma unroll
            for (int r = 0; r < 4; ++r) {
                const int row = i0 + wr * 64 + mt * 16 + quad * 4 + r;
                if (MODE == 1) {
                    const float dsc = rsqrtf(degv[row]);
                    Co[(size_t)row * ldc + col] = dsc * acc[mt][nt][r] + bias[col];
                } else {
                    Co[(size_t)row * ldc + col] = acc[mt][nt][r];
                }
            }
        }
    }
}

// Tb[idx] = bf16(sum over 4 split-K fp32 partials)
__global__ __launch_bounds__(256) void reduce4_kernel(
    const float4* __restrict__ P, unsigned short* __restrict__ Tb) {
    const size_t stride = (size_t)NROWS * FDIM / 4;   // float4 elems per partial
    #pragma unroll
    for (int p = 0; p < 4; ++p) {
        const size_t idx = (size_t)blockIdx.x * 1024 + p * 256 + threadIdx.x;
        const float4 a = P[idx];
        const float4 b = P[idx + stride];
        const float4 c = P[idx + 2 * stride];
        const float4 d = P[idx + 3 * stride];
        ushort4 o;
        o.x = f2bf(a.x + b.x + c.x + d.x);
        o.y = f2bf(a.y + b.y + c.y + d.y);
        o.z = f2bf(a.z + b.z + c.z + d.z);
        o.w = f2bf(a.w + b.w + c.w + d.w);
        *(ushort4*)&Tb[idx * 4] = o;
    }
}

extern "C" void kernel_launch(void* const* d_in, const int* in_sizes, int n_in,
                              void* d_out, int out_size, void* d_ws, size_t ws_size,
                              hipStream_t stream) {
    const float* x      = (const float*)d_in[0];
    const float* graph  = (const float*)d_in[1];
    const float* weight = (const float*)d_in[2];
    const float* bias   = (const float*)d_in[3];
    float* out = (float*)d_out;

    char* ws = (char*)d_ws;
    const size_t GT_B  = (size_t)NROWS * NROWS * 2;   // 134.2 MB: gT bf16
    const size_t XST_B = (size_t)FDIM * NROWS * 2;    // 8.4 MB: xsT bf16
    const size_t WT_B  = (size_t)FDIM * FDIM * 2;     // 0.5 MB: wT bf16
    const size_t TB_B  = (size_t)NROWS * FDIM * 2;    // 8.4 MB: Tb bf16
    const size_t DEG_B = (size_t)NROWS * 4;           // deg fp32
    unsigned short* gT  = (unsigned short*)(ws);
    unsigned short* xsT = (unsigned short*)(ws + GT_B);
    unsigned short* wT  = (unsigned short*)(ws + GT_B + XST_B);
    unsigned short* Tb  = (unsigned short*)(ws + GT_B + XST_B + WT_B);
    float* deg          = (float*)(ws + GT_B + XST_B + WT_B + TB_B);
    float* P            = (float*)(ws + GT_B + XST_B + WT_B + TB_B + DEG_B); // 64 MB

    hipLaunchKernelGGL(transpose_bf16_kernel, dim3(NROWS / 64, NROWS / 128), dim3(256), 0, stream,
                       graph, gT);
    hipLaunchKernelGGL(rowsum_kernel, dim3(NROWS / 4), dim3(256), 0, stream, gT, deg);
    hipLaunchKernelGGL(transpose_scale_kernel, dim3(FDIM / 64, NROWS / 64), dim3(256), 0, stream,
                       x, xsT, NROWS, FDIM, deg);
    hipLaunchKernelGGL(transpose_scale_kernel, dim3(FDIM / 64, FDIM / 64), dim3(256), 0, stream,
                       weight, wT, FDIM, FDIM, (const float*)nullptr);
    // T = G^T @ (d*x):  M=8192, N=512, K=8192, split-K=4 -> fp32 partials
    hipLaunchKernelGGL((gemm_nt_kernel<128, 2>), dim3(NROWS / 128, FDIM / 128, 4), dim3(256), 0, stream,
                       gT, xsT, NROWS / 4, NROWS, NROWS, P, (size_t)NROWS * FDIM,
                       (const float*)nullptr, (const float*)nullptr, FDIM);
    hipLaunchKernelGGL(reduce4_kernel, dim3(NROWS * FDIM / 4096), dim3(256), 0, stream,
                       (const float4*)P, Tb);
    // y = diag(d) * (T @ W) + bias:  M=8192, N=512, K=512
    hipLaunchKernelGGL((gemm_nt_kernel<64, 1>), dim3(NROWS / 128, FDIM / 64, 1), dim3(256), 0, stream,
                       Tb, wT, FDIM, FDIM, FDIM, out, (size_t)0,
                       deg, bias, FDIM);
}